// Round 6
// baseline (291.118 us; speedup 1.0000x reference)
//
#include <hip/hip_runtime.h>
#include <hip/hip_cooperative_groups.h>
#include <hip/hip_bf16.h>
#include <cstdint>

namespace cg = cooperative_groups;

typedef __bf16 bf16x8 __attribute__((ext_vector_type(8)));
typedef float f32x4 __attribute__((ext_vector_type(4)));

struct SharedMem {
  unsigned short As[2][4096];
  unsigned short Bs[2][4096];
};  // exactly 32768 B

__device__ __forceinline__ unsigned short f2bf(float f) {
  union { float f; uint32_t u; } a; a.f = f;
  uint32_t r = a.u + 0x7fffu + ((a.u >> 16) & 1u);
  return (unsigned short)(r >> 16);
}
__device__ __forceinline__ void gload_lds16(const unsigned short* g, unsigned short* l) {
  __builtin_amdgcn_global_load_lds(
      (const __attribute__((address_space(1))) void*)g,
      (__attribute__((address_space(3))) void*)l, 16, 0, 0);
}

// ---- GEMM tile core: 128 x (NJ*32) tile, BK=32, double-buffered LDS, ----
// ---- XOR-swizzled (conflict-free, verified R1). NJ=4 -> BN=128; NJ=2 -> BN=64.
template <int NJ>
__device__ __forceinline__ void gemm_tile_core(
    const unsigned short* __restrict__ A, const unsigned short* __restrict__ Bt,
    int K, SharedMem& sh, f32x4 (&acc)[4][NJ]) {
  const int t = threadIdx.x;
  const int lane = t & 63;
  const int quad = lane >> 4;
  const int l15 = lane & 15;
  const int wave = t >> 6;
  const int wm = (wave >> 1) * 64;
  const int wn = (wave & 1) * (NJ * 16);

  const int srow = t >> 2;                              // 0..63
  const int scol = (((t & 3) ^ ((srow >> 1) & 3)) * 8); // swizzled 16B chunk
  const unsigned short* ga = A + (size_t)srow * K + scol;
  const unsigned short* gb = Bt + (size_t)srow * K + scol;
  const size_t rowskip = (size_t)64 * K;

  const int swz = (quad ^ ((l15 >> 1) & 3)) * 8;
  const int aOff = (wm + l15) * 32 + swz;
  const int bOff = (wn + l15) * 32 + swz;

#pragma unroll
  for (int i = 0; i < 4; i++)
#pragma unroll
    for (int j = 0; j < NJ; j++) acc[i][j] = (f32x4){0.f, 0.f, 0.f, 0.f};

  // prologue: stage k0=0 into buf 0 (safe: within-block sync precedes any call)
  gload_lds16(ga, &sh.As[0][t * 8]);
  gload_lds16(ga + rowskip, &sh.As[0][2048 + t * 8]);
  gload_lds16(gb, &sh.Bs[0][t * 8]);
  if (NJ == 4) gload_lds16(gb + rowskip, &sh.Bs[0][2048 + t * 8]);

  int buf = 0;
  for (int k0 = 0; k0 < K; k0 += 32, buf ^= 1) {
    __syncthreads();  // buf ready; all reads of buf^1 done
    if (k0 + 32 < K) {
      const int kn = k0 + 32;
      gload_lds16(ga + kn, &sh.As[buf ^ 1][t * 8]);
      gload_lds16(ga + rowskip + kn, &sh.As[buf ^ 1][2048 + t * 8]);
      gload_lds16(gb + kn, &sh.Bs[buf ^ 1][t * 8]);
      if (NJ == 4) gload_lds16(gb + rowskip + kn, &sh.Bs[buf ^ 1][2048 + t * 8]);
    }
    const unsigned short* aB = &sh.As[buf][aOff];
    const unsigned short* bB = &sh.Bs[buf][bOff];
    bf16x8 a[4], b[NJ];
#pragma unroll
    for (int i = 0; i < 4; i++) a[i] = *(const bf16x8*)(aB + i * 512);
#pragma unroll
    for (int j = 0; j < NJ; j++) b[j] = *(const bf16x8*)(bB + j * 512);
#pragma unroll
    for (int i = 0; i < 4; i++)
#pragma unroll
      for (int j = 0; j < NJ; j++)
        acc[i][j] = __builtin_amdgcn_mfma_f32_16x16x32_bf16(a[i], b[j], acc[i][j], 0, 0, 0);
  }
}

// ---------- phase bodies (identical in coop and fallback paths) ----------
// grid is always 1024 blocks x 256 threads.
// ws layout (102 MB): xb@0(16M) | Wt@16M(6M, dead after P1; partial[32][8192]
// overlays it) | Q@22M | K@38M | Vt@54M [4][e][s] | Sb@70M(32M)

__device__ __forceinline__ void phase0_casts(const float* __restrict__ x,
                                             const float* __restrict__ W,
                                             unsigned short* __restrict__ xb,
                                             unsigned short* __restrict__ Wt,
                                             SharedMem& sh) {
  const int bid = blockIdx.x, t = threadIdx.x;
#pragma unroll
  for (int i = 0; i < 4; i++) {
    size_t idx = (((size_t)(bid + i * 1024)) * 256 + t) * 8;
    float4 a = *(const float4*)(x + idx);
    float4 b = *(const float4*)(x + idx + 4);
    uint4 o;
    o.x = (uint32_t)f2bf(a.x) | ((uint32_t)f2bf(a.y) << 16);
    o.y = (uint32_t)f2bf(a.z) | ((uint32_t)f2bf(a.w) << 16);
    o.z = (uint32_t)f2bf(b.x) | ((uint32_t)f2bf(b.y) << 16);
    o.w = (uint32_t)f2bf(b.z) | ((uint32_t)f2bf(b.w) << 16);
    *(uint4*)(xb + idx) = o;
  }
  float* tile = (float*)sh.As;  // [32][33] floats = 4224 B scratch
  const int tx = t & 31, ty = t >> 5;
  for (int i = 0; i < 3; i++) {
    const int u = bid + i * 1024;  // 0..3071
    const int z = u >> 10, rest = u & 1023;
    const float* Wz = W + (size_t)z * 1048576;
    unsigned short* Wtz = Wt + (size_t)z * 1048576;
    const int x0 = (rest & 31) * 32, y0 = (rest >> 5) * 32;
#pragma unroll
    for (int ii = 0; ii < 32; ii += 8)
      tile[(ty + ii) * 33 + tx] = Wz[(size_t)(y0 + ty + ii) * 1024 + x0 + tx];
    __syncthreads();
#pragma unroll
    for (int ii = 0; ii < 32; ii += 8)
      Wtz[(size_t)(x0 + ty + ii) * 1024 + y0 + tx] = f2bf(tile[tx * 33 + ty + ii]);
    __syncthreads();
  }
}

__device__ __forceinline__ void phase1_qkv(const unsigned short* __restrict__ xb,
                                           const unsigned short* __restrict__ Wt,
                                           unsigned short* __restrict__ Q,
                                           unsigned short* __restrict__ Kb,
                                           unsigned short* __restrict__ Vt,
                                           SharedMem& sh) {
  const int t = threadIdx.x;
  const int lane = t & 63, quad = lane >> 4, l15 = lane & 15, wave = t >> 6;
  const int wm = (wave >> 1) * 64;
  for (int pass = 0; pass < 2; pass++) {
    const int v = blockIdx.x + pass * 1024;
    if (v >= 1536) break;  // uniform per block
    const int z = v >> 9, mt = (v >> 3) & 63, nt = v & 7;
    const unsigned short* A = xb + (size_t)mt * 128 * 1024;
    const unsigned short* Bt = Wt + (size_t)z * 1048576 + (size_t)nt * 128 * 1024;
    f32x4 acc[4][4];
    gemm_tile_core<4>(A, Bt, 1024, sh, acc);
    const int mbase = mt * 128 + wm + quad * 4;
    const int nbase = nt * 128 + (wave & 1) * 64 + l15;
    if (z < 2) {
      unsigned short* C = (z == 0) ? Q : Kb;
#pragma unroll
      for (int mi = 0; mi < 4; mi++)
#pragma unroll
        for (int ni = 0; ni < 4; ni++) {
          const int m = mbase + mi * 16, n = nbase + ni * 16;
#pragma unroll
          for (int r = 0; r < 4; r++)
            C[(size_t)(m + r) * 1024 + n] = f2bf(acc[mi][ni][r]);
        }
    } else {  // Vt[b][e=n][s] <- acc, m = b*2048 + s
#pragma unroll
      for (int mi = 0; mi < 4; mi++) {
        const int m = mbase + mi * 16;
        const int b = m >> 11, s = m & 2047;
#pragma unroll
        for (int ni = 0; ni < 4; ni++) {
          const int n = nbase + ni * 16;
          uint2 val;
          val.x = (uint32_t)f2bf(acc[mi][ni][0]) | ((uint32_t)f2bf(acc[mi][ni][1]) << 16);
          val.y = (uint32_t)f2bf(acc[mi][ni][2]) | ((uint32_t)f2bf(acc[mi][ni][3]) << 16);
          *(uint2*)(Vt + (size_t)b * 2097152 + (size_t)n * 2048 + s) = val;
        }
      }
    }
  }
}

__device__ __forceinline__ void phase2_scores(const unsigned short* __restrict__ Q,
                                              const unsigned short* __restrict__ Kb,
                                              unsigned short* __restrict__ Sb,
                                              float* __restrict__ partial,
                                              SharedMem& sh) {
  const int t = threadIdx.x;
  const int lane = t & 63, quad = lane >> 4, l15 = lane & 15, wave = t >> 6;
  const int wm = (wave >> 1) * 64;
  const int v = blockIdx.x;
  const int z = v >> 8, mt = (v >> 4) & 15, nt = v & 15;
  const unsigned short* A = Q + (size_t)z * 2097152 + (size_t)mt * 128 * 1024;
  const unsigned short* Bt = Kb + (size_t)z * 2097152 + (size_t)nt * 128 * 1024;
  f32x4 acc[4][4];
  gemm_tile_core<4>(A, Bt, 1024, sh, acc);
  unsigned short* C = Sb + (size_t)z * 4194304;
  const int mbase = mt * 128 + wm + quad * 4;
  const int nbase = nt * 128 + (wave & 1) * 64 + l15;
  const int j = nt * 2 + (wave & 1);
#pragma unroll
  for (int mi = 0; mi < 4; mi++) {
#pragma unroll
    for (int r = 0; r < 4; r++) {
      const int m = mbase + mi * 16 + r;
      float s = 0.f;
#pragma unroll
      for (int ni = 0; ni < 4; ni++) {
        const float e = __expf(acc[mi][ni][r] * 0.03125f);
        C[(size_t)m * 2048 + nbase + ni * 16] = f2bf(e);
        s += e;
      }
      s += __shfl_xor(s, 1);
      s += __shfl_xor(s, 2);
      s += __shfl_xor(s, 4);
      s += __shfl_xor(s, 8);
      if (l15 == 0) partial[(size_t)j * 8192 + (size_t)z * 2048 + m] = s;
    }
  }
}

__device__ __forceinline__ void phase3_pv(const unsigned short* __restrict__ Sb,
                                          const unsigned short* __restrict__ Vt,
                                          const float* __restrict__ partial,
                                          float* __restrict__ out,
                                          SharedMem& sh) {
  const int t = threadIdx.x;
  const int lane = t & 63, quad = lane >> 4, l15 = lane & 15, wave = t >> 6;
  const int wm = (wave >> 1) * 64;
  const int v = blockIdx.x;
  const int z = v >> 8, mt = (v >> 4) & 15, et = v & 15;
  const unsigned short* A = Sb + (size_t)z * 4194304 + (size_t)mt * 128 * 2048;
  const unsigned short* Bt = Vt + (size_t)z * 2097152 + (size_t)et * 64 * 2048;
  f32x4 acc[4][2];
  gemm_tile_core<2>(A, Bt, 2048, sh, acc);
  __syncthreads();  // all LDS fragment reads done -> As reusable
  float* rowinv = (float*)sh.As;
  if (t < 128) {
    const size_t grow = (size_t)z * 2048 + mt * 128 + t;
    float s = 0.f;
#pragma unroll 8
    for (int j = 0; j < 32; j++) s += partial[(size_t)j * 8192 + grow];
    rowinv[t] = 1.f / s;
  }
  __syncthreads();
  float* C = out + (size_t)z * 2097152;
  const int mbase = mt * 128 + wm + quad * 4;
  const int nbase = et * 64 + (wave & 1) * 32 + l15;
#pragma unroll
  for (int mi = 0; mi < 4; mi++) {
#pragma unroll
    for (int r = 0; r < 4; r++) {
      const int m = mbase + mi * 16 + r;
      const float inv = rowinv[m & 127];
#pragma unroll
      for (int ni = 0; ni < 2; ni++)
        C[(size_t)m * 1024 + nbase + ni * 16] = acc[mi][ni][r] * inv;
    }
  }
}

// ---------- cooperative single-kernel path ----------
__global__ void __launch_bounds__(256, 4)
fused_attn(const float* __restrict__ x, const float* __restrict__ W,
           float* __restrict__ out, char* __restrict__ ws) {
  __shared__ SharedMem sh;
  unsigned short* xb = (unsigned short*)(ws);
  unsigned short* Wt = (unsigned short*)(ws + (16ll << 20));
  float* partial     = (float*)(ws + (16ll << 20));  // overlays Wt after P1
  unsigned short* Q  = (unsigned short*)(ws + (22ll << 20));
  unsigned short* Kb = (unsigned short*)(ws + (38ll << 20));
  unsigned short* Vt = (unsigned short*)(ws + (54ll << 20));
  unsigned short* Sb = (unsigned short*)(ws + (70ll << 20));
  cg::grid_group grid = cg::this_grid();

  phase0_casts(x, W, xb, Wt, sh);
  grid.sync();
  phase1_qkv(xb, Wt, Q, Kb, Vt, sh);
  grid.sync();
  phase2_scores(Q, Kb, Sb, partial, sh);
  grid.sync();
  phase3_pv(Sb, Vt, partial, out, sh);
}

// ---------- fallback multi-dispatch path (same bodies) ----------
template <int P>
__global__ void __launch_bounds__(256)
phase_kernel(const float* __restrict__ x, const float* __restrict__ W,
             float* __restrict__ out, char* __restrict__ ws) {
  __shared__ SharedMem sh;
  unsigned short* xb = (unsigned short*)(ws);
  unsigned short* Wt = (unsigned short*)(ws + (16ll << 20));
  float* partial     = (float*)(ws + (16ll << 20));
  unsigned short* Q  = (unsigned short*)(ws + (22ll << 20));
  unsigned short* Kb = (unsigned short*)(ws + (38ll << 20));
  unsigned short* Vt = (unsigned short*)(ws + (54ll << 20));
  unsigned short* Sb = (unsigned short*)(ws + (70ll << 20));
  if (P == 0) phase0_casts(x, W, xb, Wt, sh);
  else if (P == 1) phase1_qkv(xb, Wt, Q, Kb, Vt, sh);
  else if (P == 2) phase2_scores(Q, Kb, Sb, partial, sh);
  else phase3_pv(Sb, Vt, partial, out, sh);
}

extern "C" void kernel_launch(void* const* d_in, const int* in_sizes, int n_in,
                              void* d_out, int out_size, void* d_ws, size_t ws_size,
                              hipStream_t stream) {
  const float* x = (const float*)d_in[0];
  const float* W = (const float*)d_in[1];
  float* out = (float*)d_out;
  char* ws = (char*)d_ws;

  int nb = 0;
  bool coop =
      (hipOccupancyMaxActiveBlocksPerMultiprocessor(&nb, (const void*)fused_attn, 256, 0) ==
       hipSuccess) && nb >= 4;
  if (coop) {
    void* args[] = {(void*)&x, (void*)&W, (void*)&out, (void*)&ws};
    coop = (hipLaunchCooperativeKernel((void*)fused_attn, dim3(1024), dim3(256), args, 0,
                                       stream) == hipSuccess);
  }
  if (!coop) {
    phase_kernel<0><<<1024, 256, 0, stream>>>(x, W, out, ws);
    phase_kernel<1><<<1024, 256, 0, stream>>>(x, W, out, ws);
    phase_kernel<2><<<1024, 256, 0, stream>>>(x, W, out, ws);
    phase_kernel<3><<<1024, 256, 0, stream>>>(x, W, out, ws);
  }
}

// Round 7
// 290.483 us; speedup vs baseline: 1.0022x; 1.0022x over previous
//
#include <hip/hip_runtime.h>
#include <hip/hip_bf16.h>
#include <cstdint>

typedef __bf16 bf16x8 __attribute__((ext_vector_type(8)));
typedef float f32x4 __attribute__((ext_vector_type(4)));

struct SharedMem {
  unsigned short As[2][4096];
  unsigned short Bs[2][4096];
};  // exactly 32768 B

__device__ __forceinline__ unsigned short f2bf(float f) {
  union { float f; uint32_t u; } a; a.f = f;
  uint32_t r = a.u + 0x7fffu + ((a.u >> 16) & 1u);
  return (unsigned short)(r >> 16);
}
__device__ __forceinline__ void gload_lds16(const unsigned short* g, unsigned short* l) {
  __builtin_amdgcn_global_load_lds(
      (const __attribute__((address_space(1))) void*)g,
      (__attribute__((address_space(3))) void*)l, 16, 0, 0);
}

// ---- GEMM tile core: 128 x (NJ*32) tile, BK=32, double-buffered LDS, ----
// ---- XOR-swizzled (conflict-free, verified R1). NJ=4 -> BN=128; NJ=2 -> BN=64.
template <int NJ>
__device__ __forceinline__ void gemm_tile_core(
    const unsigned short* __restrict__ A, const unsigned short* __restrict__ Bt,
    int K, SharedMem& sh, f32x4 (&acc)[4][NJ]) {
  const int t = threadIdx.x;
  const int lane = t & 63;
  const int quad = lane >> 4;
  const int l15 = lane & 15;
  const int wave = t >> 6;
  const int wm = (wave >> 1) * 64;
  const int wn = (wave & 1) * (NJ * 16);

  const int srow = t >> 2;                              // 0..63
  const int scol = (((t & 3) ^ ((srow >> 1) & 3)) * 8); // swizzled 16B chunk
  const unsigned short* ga = A + (size_t)srow * K + scol;
  const unsigned short* gb = Bt + (size_t)srow * K + scol;
  const size_t rowskip = (size_t)64 * K;

  const int swz = (quad ^ ((l15 >> 1) & 3)) * 8;
  const int aOff = (wm + l15) * 32 + swz;
  const int bOff = (wn + l15) * 32 + swz;

#pragma unroll
  for (int i = 0; i < 4; i++)
#pragma unroll
    for (int j = 0; j < NJ; j++) acc[i][j] = (f32x4){0.f, 0.f, 0.f, 0.f};

  // prologue: stage k0=0 into buf 0
  gload_lds16(ga, &sh.As[0][t * 8]);
  gload_lds16(ga + rowskip, &sh.As[0][2048 + t * 8]);
  gload_lds16(gb, &sh.Bs[0][t * 8]);
  if (NJ == 4) gload_lds16(gb + rowskip, &sh.Bs[0][2048 + t * 8]);

  int buf = 0;
  for (int k0 = 0; k0 < K; k0 += 32, buf ^= 1) {
    __syncthreads();  // buf ready; all reads of buf^1 done
    if (k0 + 32 < K) {
      const int kn = k0 + 32;
      gload_lds16(ga + kn, &sh.As[buf ^ 1][t * 8]);
      gload_lds16(ga + rowskip + kn, &sh.As[buf ^ 1][2048 + t * 8]);
      gload_lds16(gb + kn, &sh.Bs[buf ^ 1][t * 8]);
      if (NJ == 4) gload_lds16(gb + rowskip + kn, &sh.Bs[buf ^ 1][2048 + t * 8]);
    }
    const unsigned short* aB = &sh.As[buf][aOff];
    const unsigned short* bB = &sh.Bs[buf][bOff];
    bf16x8 a[4], b[NJ];
#pragma unroll
    for (int i = 0; i < 4; i++) a[i] = *(const bf16x8*)(aB + i * 512);
#pragma unroll
    for (int j = 0; j < NJ; j++) b[j] = *(const bf16x8*)(bB + j * 512);
#pragma unroll
    for (int i = 0; i < 4; i++)
#pragma unroll
      for (int j = 0; j < NJ; j++)
        acc[i][j] = __builtin_amdgcn_mfma_f32_16x16x32_bf16(a[i], b[j], acc[i][j], 0, 0, 0);
  }
}

// ---------- phase bodies; grid is always 1024 blocks x 256 threads ----------
// ws layout (102 MB): xb@0(16M) | Wt@16M(6M, dead after P1; partial[32][8192]
// overlays it) | Q@22M | K@38M | Vt@54M [4][e][s] | Sb@70M(32M)

__device__ __forceinline__ void phase0_casts(const float* __restrict__ x,
                                             const float* __restrict__ W,
                                             unsigned short* __restrict__ xb,
                                             unsigned short* __restrict__ Wt,
                                             SharedMem& sh) {
  const int bid = blockIdx.x, t = threadIdx.x;
#pragma unroll
  for (int i = 0; i < 4; i++) {
    size_t idx = (((size_t)(bid + i * 1024)) * 256 + t) * 8;
    float4 a = *(const float4*)(x + idx);
    float4 b = *(const float4*)(x + idx + 4);
    uint4 o;
    o.x = (uint32_t)f2bf(a.x) | ((uint32_t)f2bf(a.y) << 16);
    o.y = (uint32_t)f2bf(a.z) | ((uint32_t)f2bf(a.w) << 16);
    o.z = (uint32_t)f2bf(b.x) | ((uint32_t)f2bf(b.y) << 16);
    o.w = (uint32_t)f2bf(b.z) | ((uint32_t)f2bf(b.w) << 16);
    *(uint4*)(xb + idx) = o;
  }
  float* tile = (float*)sh.As;  // [32][33] floats = 4224 B scratch
  const int tx = t & 31, ty = t >> 5;
  for (int i = 0; i < 3; i++) {
    const int u = bid + i * 1024;  // 0..3071
    const int z = u >> 10, rest = u & 1023;
    const float* Wz = W + (size_t)z * 1048576;
    unsigned short* Wtz = Wt + (size_t)z * 1048576;
    const int x0 = (rest & 31) * 32, y0 = (rest >> 5) * 32;
#pragma unroll
    for (int ii = 0; ii < 32; ii += 8)
      tile[(ty + ii) * 33 + tx] = Wz[(size_t)(y0 + ty + ii) * 1024 + x0 + tx];
    __syncthreads();
#pragma unroll
    for (int ii = 0; ii < 32; ii += 8)
      Wtz[(size_t)(x0 + ty + ii) * 1024 + y0 + tx] = f2bf(tile[tx * 33 + ty + ii]);
    __syncthreads();
  }
}

__device__ __forceinline__ void phase1_qkv(const unsigned short* __restrict__ xb,
                                           const unsigned short* __restrict__ Wt,
                                           unsigned short* __restrict__ Q,
                                           unsigned short* __restrict__ Kb,
                                           unsigned short* __restrict__ Vt,
                                           SharedMem& sh) {
  const int t = threadIdx.x;
  const int lane = t & 63, quad = lane >> 4, l15 = lane & 15, wave = t >> 6;
  const int wm = (wave >> 1) * 64;
  for (int pass = 0; pass < 2; pass++) {
    const int v = blockIdx.x + pass * 1024;
    if (v >= 1536) break;  // uniform per block
    const int z = v >> 9, mt = (v >> 3) & 63, nt = v & 7;
    const unsigned short* A = xb + (size_t)mt * 128 * 1024;
    const unsigned short* Bt = Wt + (size_t)z * 1048576 + (size_t)nt * 128 * 1024;
    f32x4 acc[4][4];
    gemm_tile_core<4>(A, Bt, 1024, sh, acc);
    const int mbase = mt * 128 + wm + quad * 4;
    const int nbase = nt * 128 + (wave & 1) * 64 + l15;
    if (z < 2) {
      unsigned short* C = (z == 0) ? Q : Kb;
#pragma unroll
      for (int mi = 0; mi < 4; mi++)
#pragma unroll
        for (int ni = 0; ni < 4; ni++) {
          const int m = mbase + mi * 16, n = nbase + ni * 16;
#pragma unroll
          for (int r = 0; r < 4; r++)
            C[(size_t)(m + r) * 1024 + n] = f2bf(acc[mi][ni][r]);
        }
    } else {  // Vt[b][e=n][s] <- acc, m = b*2048 + s
#pragma unroll
      for (int mi = 0; mi < 4; mi++) {
        const int m = mbase + mi * 16;
        const int b = m >> 11, s = m & 2047;
#pragma unroll
        for (int ni = 0; ni < 4; ni++) {
          const int n = nbase + ni * 16;
          uint2 val;
          val.x = (uint32_t)f2bf(acc[mi][ni][0]) | ((uint32_t)f2bf(acc[mi][ni][1]) << 16);
          val.y = (uint32_t)f2bf(acc[mi][ni][2]) | ((uint32_t)f2bf(acc[mi][ni][3]) << 16);
          *(uint2*)(Vt + (size_t)b * 2097152 + (size_t)n * 2048 + s) = val;
        }
      }
    }
    if (pass == 0) __syncthreads();  // LDS safe before next tile
  }
}

__device__ __forceinline__ void phase2_scores(const unsigned short* __restrict__ Q,
                                              const unsigned short* __restrict__ Kb,
                                              unsigned short* __restrict__ Sb,
                                              float* __restrict__ partial,
                                              SharedMem& sh) {
  const int t = threadIdx.x;
  const int lane = t & 63, quad = lane >> 4, l15 = lane & 15, wave = t >> 6;
  const int wm = (wave >> 1) * 64;
  const int v = blockIdx.x;
  const int z = v >> 8, mt = (v >> 4) & 15, nt = v & 15;
  const unsigned short* A = Q + (size_t)z * 2097152 + (size_t)mt * 128 * 1024;
  const unsigned short* Bt = Kb + (size_t)z * 2097152 + (size_t)nt * 128 * 1024;
  f32x4 acc[4][4];
  gemm_tile_core<4>(A, Bt, 1024, sh, acc);
  unsigned short* C = Sb + (size_t)z * 4194304;
  const int mbase = mt * 128 + wm + quad * 4;
  const int nbase = nt * 128 + (wave & 1) * 64 + l15;
  const int j = nt * 2 + (wave & 1);
#pragma unroll
  for (int mi = 0; mi < 4; mi++) {
#pragma unroll
    for (int r = 0; r < 4; r++) {
      const int m = mbase + mi * 16 + r;
      float s = 0.f;
#pragma unroll
      for (int ni = 0; ni < 4; ni++) {
        const float e = __expf(acc[mi][ni][r] * 0.03125f);
        C[(size_t)m * 2048 + nbase + ni * 16] = f2bf(e);
        s += e;
      }
      s += __shfl_xor(s, 1);
      s += __shfl_xor(s, 2);
      s += __shfl_xor(s, 4);
      s += __shfl_xor(s, 8);
      if (l15 == 0) partial[(size_t)j * 8192 + (size_t)z * 2048 + m] = s;
    }
  }
}

__device__ __forceinline__ void phase3_pv(const unsigned short* __restrict__ Sb,
                                          const unsigned short* __restrict__ Vt,
                                          const float* __restrict__ partial,
                                          float* __restrict__ out,
                                          SharedMem& sh) {
  const int t = threadIdx.x;
  const int lane = t & 63, quad = lane >> 4, l15 = lane & 15, wave = t >> 6;
  const int wm = (wave >> 1) * 64;
  const int v = blockIdx.x;
  const int z = v >> 8, mt = (v >> 4) & 15, et = v & 15;
  const unsigned short* A = Sb + (size_t)z * 4194304 + (size_t)mt * 128 * 2048;
  const unsigned short* Bt = Vt + (size_t)z * 2097152 + (size_t)et * 64 * 2048;
  f32x4 acc[4][2];
  gemm_tile_core<2>(A, Bt, 2048, sh, acc);
  __syncthreads();  // all LDS fragment reads done -> As reusable
  float* rowinv = (float*)sh.As;
  if (t < 128) {
    const size_t grow = (size_t)z * 2048 + mt * 128 + t;
    float s = 0.f;
#pragma unroll 8
    for (int j = 0; j < 32; j++) s += partial[(size_t)j * 8192 + grow];
    rowinv[t] = 1.f / s;
  }
  __syncthreads();
  float* C = out + (size_t)z * 2097152;
  const int mbase = mt * 128 + wm + quad * 4;
  const int nbase = et * 64 + (wave & 1) * 32 + l15;
#pragma unroll
  for (int mi = 0; mi < 4; mi++) {
#pragma unroll
    for (int r = 0; r < 4; r++) {
      const int m = mbase + mi * 16 + r;
      const float inv = rowinv[m & 127];
#pragma unroll
      for (int ni = 0; ni < 2; ni++)
        C[(size_t)m * 1024 + nbase + ni * 16] = acc[mi][ni][r] * inv;
    }
  }
}

// ---------- multi-dispatch (coop reverted: grid.sync measured 673 us @0.5% MFMA) ----------
template <int P>
__global__ void __launch_bounds__(256)
phase_kernel(const float* __restrict__ x, const float* __restrict__ W,
             float* __restrict__ out, char* __restrict__ ws) {
  __shared__ SharedMem sh;
  unsigned short* xb = (unsigned short*)(ws);
  unsigned short* Wt = (unsigned short*)(ws + (16ll << 20));
  float* partial     = (float*)(ws + (16ll << 20));
  unsigned short* Q  = (unsigned short*)(ws + (22ll << 20));
  unsigned short* Kb = (unsigned short*)(ws + (38ll << 20));
  unsigned short* Vt = (unsigned short*)(ws + (54ll << 20));
  unsigned short* Sb = (unsigned short*)(ws + (70ll << 20));
  if (P == 0) phase0_casts(x, W, xb, Wt, sh);
  else if (P == 1) phase1_qkv(xb, Wt, Q, Kb, Vt, sh);
  else if (P == 2) phase2_scores(Q, Kb, Sb, partial, sh);
  else phase3_pv(Sb, Vt, partial, out, sh);
}

extern "C" void kernel_launch(void* const* d_in, const int* in_sizes, int n_in,
                              void* d_out, int out_size, void* d_ws, size_t ws_size,
                              hipStream_t stream) {
  const float* x = (const float*)d_in[0];
  const float* W = (const float*)d_in[1];
  float* out = (float*)d_out;
  char* ws = (char*)d_ws;
  phase_kernel<0><<<1024, 256, 0, stream>>>(x, W, out, ws);
  phase_kernel<1><<<1024, 256, 0, stream>>>(x, W, out, ws);
  phase_kernel<2><<<1024, 256, 0, stream>>>(x, W, out, ws);
  phase_kernel<3><<<1024, 256, 0, stream>>>(x, W, out, ws);
}